// Round 9
// baseline (222.508 us; speedup 1.0000x reference)
//
#include <hip/hip_runtime.h>

#define N_NODES 100000
#define D_IN 32
#define H 64
#define EPS 1e-5f
#define RSTR 32     // bucket row: 32 entry slots (128B)
#define CAP 32
#define OV_CAP 32768
#define SRC_HALF 50000

typedef float floatx2 __attribute__((ext_vector_type(2)));

__device__ __forceinline__ unsigned short f2bf(float f) {
    union { float f; unsigned int u; } c; c.f = f;
    unsigned int b = c.u + 0x7FFFu + ((c.u >> 16) & 1u);   // RNE
    return (unsigned short)(b >> 16);
}
__device__ __forceinline__ float bf2f(unsigned short s) {
    union { unsigned int u; float f; } c; c.u = ((unsigned int)s) << 16;
    return c.f;
}

// ================= fused: scatter + MLP (exact R0 baseline — control) =================
__global__ __launch_bounds__(256, 2) void fused_kernel(
    const float* __restrict__ x,
    const float* __restrict__ W1, const float* __restrict__ b1,
    const float* __restrict__ g1, const float* __restrict__ be1,
    const float* __restrict__ W2, const float* __restrict__ b2,
    const float* __restrict__ g2, const float* __restrict__ be2,
    unsigned short* __restrict__ hb, unsigned char* __restrict__ hb8,
    const int* __restrict__ ei, int* __restrict__ cnt, int* __restrict__ bkt,
    int* __restrict__ ovCnt, int2* __restrict__ ov,
    int E, int SB, int TOT)
{
    const int i = blockIdx.x;
    const int before = (int)((long long)i * SB / TOT);
    const int after  = (int)((long long)(i + 1) * SB / TOT);

    if (after > before) {
        // ---------------- scatter: 8 edges/thread ----------------
        int t = before * 256 + threadIdx.x;
        int e0 = t * 8;
        if (e0 >= E) return;

        int rows[8], cols[8], pos[8];
        if (e0 + 7 < E) {
            int4 r0 = *(const int4*)(ei + e0);
            int4 r1 = *(const int4*)(ei + e0 + 4);
            int4 c0 = *(const int4*)(ei + E + e0);
            int4 c1 = *(const int4*)(ei + E + e0 + 4);
            rows[0]=r0.x; rows[1]=r0.y; rows[2]=r0.z; rows[3]=r0.w;
            rows[4]=r1.x; rows[5]=r1.y; rows[6]=r1.z; rows[7]=r1.w;
            cols[0]=c0.x; cols[1]=c0.y; cols[2]=c0.z; cols[3]=c0.w;
            cols[4]=c1.x; cols[5]=c1.y; cols[6]=c1.z; cols[7]=c1.w;
        } else {
#pragma unroll
            for (int j = 0; j < 8; ++j) {
                int e = e0 + j;
                if (e < E) { rows[j] = ei[e]; cols[j] = ei[E + e]; }
                else rows[j] = -1;
            }
        }
#pragma unroll
        for (int j = 0; j < 8; ++j)
            if (rows[j] >= 0) pos[j] = atomicAdd(&cnt[rows[j]], 1);
#pragma unroll
        for (int j = 0; j < 8; ++j) {
            if (rows[j] < 0) continue;
            if (pos[j] < CAP) {
                __builtin_nontemporal_store(cols[j], &bkt[rows[j] * RSTR + pos[j]]);
            } else {
                int s = atomicAdd(ovCnt, 1);
                if (s < OV_CAP) ov[s] = make_int2(rows[j], cols[j]);
            }
        }
        return;
    }

    // ---------------- MLP: thread-per-node ----------------
    int gid = (i - before) * 256 + threadIdx.x;
    int node = gid < N_NODES ? gid : N_NODES - 1;

    float xr[D_IN];
    {
        const float4* xp = (const float4*)(x + (long long)node * D_IN);
#pragma unroll
        for (int i2 = 0; i2 < D_IN / 4; ++i2) {
            float4 v = xp[i2];
            xr[4*i2+0] = v.x; xr[4*i2+1] = v.y; xr[4*i2+2] = v.z; xr[4*i2+3] = v.w;
        }
    }

    float h1[H];
#pragma unroll
    for (int jb = 0; jb < H / 4; ++jb) {
        float4 b = *(const float4*)(b1 + jb * 4);
        h1[4*jb+0] = b.x; h1[4*jb+1] = b.y; h1[4*jb+2] = b.z; h1[4*jb+3] = b.w;
    }
#pragma unroll
    for (int k = 0; k < D_IN; ++k) {
        float xk = xr[k];
#pragma unroll
        for (int jb = 0; jb < H / 4; ++jb) {
            float4 w = *(const float4*)(W1 + k * H + jb * 4);
            h1[4*jb+0] += xk * w.x; h1[4*jb+1] += xk * w.y;
            h1[4*jb+2] += xk * w.z; h1[4*jb+3] += xk * w.w;
        }
    }
    {
        float s0=0,s1=0,s2=0,s3=0, q0=0,q1=0,q2=0,q3=0;
#pragma unroll
        for (int j = 0; j < H; j += 4) {
            s0 += h1[j+0]; s1 += h1[j+1]; s2 += h1[j+2]; s3 += h1[j+3];
            q0 += h1[j+0]*h1[j+0]; q1 += h1[j+1]*h1[j+1];
            q2 += h1[j+2]*h1[j+2]; q3 += h1[j+3]*h1[j+3];
        }
        float mu  = (s0+s1+s2+s3) * (1.0f / H);
        float var = (q0+q1+q2+q3) * (1.0f / H) - mu * mu;
        float rs  = rsqrtf(var + EPS);
#pragma unroll
        for (int jb = 0; jb < H / 4; ++jb) {
            float4 g = *(const float4*)(g1 + jb * 4);
            float4 be = *(const float4*)(be1 + jb * 4);
            h1[4*jb+0] = fmaxf((h1[4*jb+0]-mu)*rs*g.x + be.x, 0.0f);
            h1[4*jb+1] = fmaxf((h1[4*jb+1]-mu)*rs*g.y + be.y, 0.0f);
            h1[4*jb+2] = fmaxf((h1[4*jb+2]-mu)*rs*g.z + be.z, 0.0f);
            h1[4*jb+3] = fmaxf((h1[4*jb+3]-mu)*rs*g.w + be.w, 0.0f);
        }
    }

    float h2[H];
#pragma unroll
    for (int jb = 0; jb < H / 4; ++jb) {
        float4 b = *(const float4*)(b2 + jb * 4);
        h2[4*jb+0] = b.x; h2[4*jb+1] = b.y; h2[4*jb+2] = b.z; h2[4*jb+3] = b.w;
    }
#pragma unroll
    for (int k = 0; k < H; ++k) {
        float hk = h1[k];
#pragma unroll
        for (int jb = 0; jb < H / 4; ++jb) {
            float4 w = *(const float4*)(W2 + k * H + jb * 4);
            h2[4*jb+0] += hk * w.x; h2[4*jb+1] += hk * w.y;
            h2[4*jb+2] += hk * w.z; h2[4*jb+3] += hk * w.w;
        }
    }
    {
        float s0=0,s1=0,s2=0,s3=0, q0=0,q1=0,q2=0,q3=0;
#pragma unroll
        for (int j = 0; j < H; j += 4) {
            s0 += h2[j+0]; s1 += h2[j+1]; s2 += h2[j+2]; s3 += h2[j+3];
            q0 += h2[j+0]*h2[j+0]; q1 += h2[j+1]*h2[j+1];
            q2 += h2[j+2]*h2[j+2]; q3 += h2[j+3]*h2[j+3];
        }
        float mu  = (s0+s1+s2+s3) * (1.0f / H);
        float var = (q0+q1+q2+q3) * (1.0f / H) - mu * mu;
        float rs  = rsqrtf(var + EPS);

        unsigned short* hp = hb + (long long)node * H;
        unsigned int w8[H / 4];
#pragma unroll
        for (int jb = 0; jb < H / 4; ++jb) {
            float4 g = *(const float4*)(g2 + jb * 4);
            float4 be = *(const float4*)(be2 + jb * 4);
            float4 v;
            v.x = fmaxf((h2[4*jb+0]-mu)*rs*g.x + be.x, 0.0f);
            v.y = fmaxf((h2[4*jb+1]-mu)*rs*g.y + be.y, 0.0f);
            v.z = fmaxf((h2[4*jb+2]-mu)*rs*g.z + be.z, 0.0f);
            v.w = fmaxf((h2[4*jb+3]-mu)*rs*g.w + be.w, 0.0f);
            ushort4 u;
            u.x = f2bf(v.x); u.y = f2bf(v.y); u.z = f2bf(v.z); u.w = f2bf(v.w);
            *(ushort4*)(hp + 4*jb) = u;
            int lo = __builtin_amdgcn_cvt_pk_fp8_f32(v.x, v.y, 0, false);
            w8[jb] = (unsigned int)__builtin_amdgcn_cvt_pk_fp8_f32(v.z, v.w, lo, true);
        }
        unsigned int* hp8 = (unsigned int*)(hb8 + (long long)node * H);
#pragma unroll
        for (int q = 0; q < H / 16; ++q)
            *(uint4*)(hp8 + q * 4) = make_uint4(w8[4*q+0], w8[4*q+1], w8[4*q+2], w8[4*q+3]);
    }
}

// ================= pull aggregation: src-split two-pass, L2-resident half-table =================
// R17 theory (MSHR model): aggr rate = miss-slots/latency. Measured: 12.5G
// random lines/s at L3 latency (R0/R8, insensitive to request width/count),
// 22G/s when table is L2-resident (R7). R7 lost the gain by touching 2x
// lines; this pass structure halves LINES PER PASS instead: pass p gathers
// only edges with src in [p*50K,(p+1)*50K) -> live table = 3.2MB half of
// hb8 (L2-resident), ~625K line-touches per pass. Pass0: partial + self ->
// out; pass1: out += partial + overflow. Wave layout = R8 dwordx4 (4 nodes
// x (quad q, group g), 8x uint4 gathers/lane, shfl_xor(4,8) butterfly).
__global__ __launch_bounds__(256, 2) void aggr_pass_kernel(
    const int* __restrict__ cnt, const int* __restrict__ bkt,
    const unsigned short* __restrict__ hb, const unsigned char* __restrict__ hb8,
    float* __restrict__ out,
    const int* __restrict__ ovCnt, const int2* __restrict__ ov,
    int srcLo, int srcHi, int isFinal)
{
    const int t    = threadIdx.x & 63;
    const int sub  = t >> 4;                       // 4 nodes/wave
    const int l    = t & 15;
    const int q    = l & 3;                        // 16B quad within 64B row
    const int g    = l >> 2;                       // edge-group: 8 contiguous edges
    const int wave = blockIdx.x * 4 + (threadIdx.x >> 6);
    const int node = wave * 4 + sub;               // grid exact: 6250*16 = 100000

    int m = cnt[node];
    if (m > CAP) m = CAP;
    const int base = node * RSTR;

    // 2 VMEM: this lane's 8 contiguous edge indices [g*8, g*8+8)
    int4 ea = *(const int4*)(bkt + base + g * 8);
    int4 eb = *(const int4*)(bkt + base + g * 8 + 4);
    int ed[8] = { ea.x, ea.y, ea.z, ea.w, eb.x, eb.y, eb.z, eb.w };
    const int e0 = g * 8;

    bool keep[8];
#pragma unroll
    for (int k = 0; k < 8; ++k)
        keep[k] = (e0 + k < m) && (ed[k] >= srcLo) && (ed[k] < srcHi);

    const uint4* h84 = (const uint4*)hb8;          // row = 4 uint4 (64B)

    float s[16];
#pragma unroll
    for (int j = 0; j < 16; ++j) s[j] = 0.f;

    // up to 8 VMEM: one 16B gather per in-range edge (quad q of that row)
    uint4 vv[8];
#pragma unroll
    for (int k = 0; k < 8; ++k)
        if (keep[k]) vv[k] = h84[(ed[k] << 2) + q];

#pragma unroll
    for (int k = 0; k < 8; ++k) {
        if (keep[k]) {
            unsigned int w[4] = { vv[k].x, vv[k].y, vv[k].z, vv[k].w };
#pragma unroll
            for (int u = 0; u < 4; ++u) {
                floatx2 p0 = __builtin_amdgcn_cvt_pk_f32_fp8(w[u], false);
                floatx2 p1 = __builtin_amdgcn_cvt_pk_f32_fp8(w[u], true);
                s[4*u+0] += p0.x; s[4*u+1] += p0.y;
                s[4*u+2] += p1.x; s[4*u+3] += p1.y;
            }
        }
    }

    // butterfly over the 4 edge-groups (lanes differing in t bits 2-3)
#pragma unroll
    for (int j = 0; j < 16; ++j) {
        s[j] += __shfl_xor(s[j], 4, 64);
        s[j] += __shfl_xor(s[j], 8, 64);
    }

    // this lane owns channels co..co+3
    const int co = q * 16 + g * 4;
    float a0 = s[g*4+0], a1 = s[g*4+1], a2 = s[g*4+2], a3 = s[g*4+3];

    if (!isFinal) {
        // pass 0: add self term (bf16, sequential), overwrite out
        uint2 sv = *(const uint2*)(hb + ((long long)node << 6) + co);
        a0 += bf2f((unsigned short)(sv.x & 0xFFFFu));
        a1 += bf2f((unsigned short)(sv.x >> 16));
        a2 += bf2f((unsigned short)(sv.y & 0xFFFFu));
        a3 += bf2f((unsigned short)(sv.y >> 16));
    } else {
        // pass 1: accumulate onto pass-0 partial; drain overflow exactly once
        float4 prev = *(const float4*)(out + ((long long)node << 6) + co);
        a0 += prev.x; a1 += prev.y; a2 += prev.z; a3 += prev.w;

        int nov = *ovCnt; if (nov > OV_CAP) nov = OV_CAP;
        for (int i = 0; i < nov; ++i) {
            int2 rc = ov[i];
            if (rc.x == node) {
                uint2 vo = *(const uint2*)(hb + ((long long)rc.y << 6) + co);
                a0 += bf2f((unsigned short)(vo.x & 0xFFFFu));
                a1 += bf2f((unsigned short)(vo.x >> 16));
                a2 += bf2f((unsigned short)(vo.y & 0xFFFFu));
                a3 += bf2f((unsigned short)(vo.y >> 16));
            }
        }
    }

    *(float4*)(out + ((long long)node << 6) + co) = make_float4(a0, a1, a2, a3);
}

extern "C" void kernel_launch(void* const* d_in, const int* in_sizes, int n_in,
                              void* d_out, int out_size, void* d_ws, size_t ws_size,
                              hipStream_t stream)
{
    const float* x   = (const float*)d_in[0];
    const int*   ei  = (const int*)d_in[1];
    const float* W1  = (const float*)d_in[2];
    const float* b1  = (const float*)d_in[3];
    const float* g1  = (const float*)d_in[4];
    const float* be1 = (const float*)d_in[5];
    const float* W2  = (const float*)d_in[6];
    const float* b2  = (const float*)d_in[7];
    const float* g2  = (const float*)d_in[8];
    const float* be2 = (const float*)d_in[9];

    float* out = (float*)d_out;

    // workspace layout (~32.7 MB)
    char* ws = (char*)d_ws;
    unsigned short* hb    = (unsigned short*)ws;        // 12,800,000 B
    unsigned char*  hb8   = (unsigned char*)(ws + 12800000); // 6,400,000 B
    int*            cnt   = (int*)(ws + 19200000);      //    400,000 B
    int*            ovCnt = (int*)(ws + 19600000);      //         64 B
    int2*           ov    = (int2*)(ws + 19600064);     //    262,144 B
    int*            bkt   = (int*)(ws + 19862208);      // 12,800,000 B (nt-written, never zeroed)

    const int E = in_sizes[1] / 2;

    (void)hipMemsetAsync(cnt, 0, 400064, stream);       // cnt + ovCnt

    const int SB = ((E + 7) / 8 + 255) / 256;           // 611 scatter blocks
    const int MB = (N_NODES + 255) / 256;               // 391 mlp blocks
    fused_kernel<<<SB + MB, 256, 0, stream>>>(
        x, W1, b1, g1, be1, W2, b2, g2, be2, hb, hb8,
        ei, cnt, bkt, ovCnt, ov, E, SB, SB + MB);

    // two src-range passes: each gathers from an L2-resident 3.2MB half-table
    aggr_pass_kernel<<<N_NODES / 16, 256, 0, stream>>>(
        cnt, bkt, hb, hb8, out, ovCnt, ov, 0, SRC_HALF, 0);
    aggr_pass_kernel<<<N_NODES / 16, 256, 0, stream>>>(
        cnt, bkt, hb, hb8, out, ovCnt, ov, SRC_HALF, N_NODES, 1);
}

// Round 10
// 211.988 us; speedup vs baseline: 1.0496x; 1.0496x over previous
//
#include <hip/hip_runtime.h>

#define N_NODES 100000
#define D_IN 32
#define H 64
#define EPS 1e-5f
#define RSTR 32     // bucket row: 32 entry slots (128B)
#define CAP 32
#define OV_CAP 32768
#define HALF 50000

typedef float floatx2 __attribute__((ext_vector_type(2)));

__device__ __forceinline__ unsigned short f2bf(float f) {
    union { float f; unsigned int u; } c; c.f = f;
    unsigned int b = c.u + 0x7FFFu + ((c.u >> 16) & 1u);   // RNE
    return (unsigned short)(b >> 16);
}
__device__ __forceinline__ float bf2f(unsigned short s) {
    union { unsigned int u; float f; } c; c.u = ((unsigned int)s) << 16;
    return c.f;
}

// ---------------- scatter for a dst-range: scan chunk, keep rows in [lo,hi) ----------------
__device__ __forceinline__ void scatter_range(
    const int* __restrict__ ei, int* __restrict__ cnt, int* __restrict__ bkt,
    int* __restrict__ ovCnt, int2* __restrict__ ov,
    int E, int chunk, int lo, int hi)
{
    int t = chunk * 256 + threadIdx.x;
    int e0 = t * 8;
    if (e0 >= E) return;

    int rows[8], cols[8], pos[8];
    if (e0 + 7 < E) {
        int4 r0 = *(const int4*)(ei + e0);
        int4 r1 = *(const int4*)(ei + e0 + 4);
        int4 c0 = *(const int4*)(ei + E + e0);
        int4 c1 = *(const int4*)(ei + E + e0 + 4);
        rows[0]=r0.x; rows[1]=r0.y; rows[2]=r0.z; rows[3]=r0.w;
        rows[4]=r1.x; rows[5]=r1.y; rows[6]=r1.z; rows[7]=r1.w;
        cols[0]=c0.x; cols[1]=c0.y; cols[2]=c0.z; cols[3]=c0.w;
        cols[4]=c1.x; cols[5]=c1.y; cols[6]=c1.z; cols[7]=c1.w;
    } else {
#pragma unroll
        for (int j = 0; j < 8; ++j) {
            int e = e0 + j;
            if (e < E) { rows[j] = ei[e]; cols[j] = ei[E + e]; }
            else rows[j] = -1;
        }
    }
#pragma unroll
    for (int j = 0; j < 8; ++j) {
        pos[j] = -1;
        if (rows[j] >= lo && rows[j] < hi)
            pos[j] = atomicAdd(&cnt[rows[j]], 1);
    }
#pragma unroll
    for (int j = 0; j < 8; ++j) {
        if (pos[j] < 0) continue;
        if (pos[j] < CAP) {
            __builtin_nontemporal_store(cols[j], &bkt[rows[j] * RSTR + pos[j]]);
        } else {
            int s = atomicAdd(ovCnt, 1);
            if (s < OV_CAP) ov[s] = make_int2(rows[j], cols[j]);
        }
    }
}

// ---------------- aggr for one node (R8 dwordx4 form) ----------------
__device__ __forceinline__ void aggr_node(
    const int* __restrict__ cnt, const int* __restrict__ bkt,
    const unsigned short* __restrict__ hb, const unsigned char* __restrict__ hb8,
    float* __restrict__ out,
    const int* __restrict__ ovCnt, const int2* __restrict__ ov,
    int node)
{
    const int t = threadIdx.x & 63;
    const int l = t & 15;
    const int q = l & 3;                           // 16B quad within 64B row
    const int g = l >> 2;                          // edge-group: 8 contiguous edges

    int m = cnt[node];
    if (m > CAP) m = CAP;
    const int base = node * RSTR;

    int4 ea = *(const int4*)(bkt + base + g * 8);
    int4 eb = *(const int4*)(bkt + base + g * 8 + 4);
    int ed[8] = { ea.x, ea.y, ea.z, ea.w, eb.x, eb.y, eb.z, eb.w };
    const int e0 = g * 8;

    const uint4* h84 = (const uint4*)hb8;          // row = 4 uint4 (64B)

    float s[16];
#pragma unroll
    for (int j = 0; j < 16; ++j) s[j] = 0.f;

    uint4 vv[8];
#pragma unroll
    for (int k = 0; k < 8; ++k)
        if (e0 + k < m) vv[k] = h84[(ed[k] << 2) + q];

#pragma unroll
    for (int k = 0; k < 8; ++k) {
        if (e0 + k < m) {
            unsigned int w[4] = { vv[k].x, vv[k].y, vv[k].z, vv[k].w };
#pragma unroll
            for (int u = 0; u < 4; ++u) {
                floatx2 p0 = __builtin_amdgcn_cvt_pk_f32_fp8(w[u], false);
                floatx2 p1 = __builtin_amdgcn_cvt_pk_f32_fp8(w[u], true);
                s[4*u+0] += p0.x; s[4*u+1] += p0.y;
                s[4*u+2] += p1.x; s[4*u+3] += p1.y;
            }
        }
    }

#pragma unroll
    for (int j = 0; j < 16; ++j) {
        s[j] += __shfl_xor(s[j], 4, 64);
        s[j] += __shfl_xor(s[j], 8, 64);
    }

    const int co = q * 16 + g * 4;
    float a0 = s[g*4+0], a1 = s[g*4+1], a2 = s[g*4+2], a3 = s[g*4+3];

    // self term
    {
        uint2 sv = *(const uint2*)(hb + ((long long)node << 6) + co);
        a0 += bf2f((unsigned short)(sv.x & 0xFFFFu));
        a1 += bf2f((unsigned short)(sv.x >> 16));
        a2 += bf2f((unsigned short)(sv.y & 0xFFFFu));
        a3 += bf2f((unsigned short)(sv.y >> 16));
    }

    // exact overflow drain (normally 0 entries; each node aggregated exactly once)
    int nov = *ovCnt; if (nov > OV_CAP) nov = OV_CAP;
    for (int i = 0; i < nov; ++i) {
        int2 rc = ov[i];
        if (rc.x == node) {
            uint2 vo = *(const uint2*)(hb + ((long long)rc.y << 6) + co);
            a0 += bf2f((unsigned short)(vo.x & 0xFFFFu));
            a1 += bf2f((unsigned short)(vo.x >> 16));
            a2 += bf2f((unsigned short)(vo.y & 0xFFFFu));
            a3 += bf2f((unsigned short)(vo.y >> 16));
        }
    }

    *(float4*)(out + ((long long)node << 6) + co) = make_float4(a0, a1, a2, a3);
}

// ================= K1: scatter(dst<50K) ∥ MLP(all nodes) =================
// R18 pipeline: break the scatter->gather dependency by dst-halves so the
// random-WRITE wall (scatter, ~24G ops/s) and random-READ wall (gather,
// ~16G lines/s) can overlap if they are separate fabric resources.
// K1: scatter half0 + full MLP.  K2: scatter half1 ∥ aggr half0 (the
// experiment: max vs sum).  K3: aggr half1.  R3 proved full-edge-scan with
// range-keep costs nothing extra.
__global__ __launch_bounds__(256, 2) void k1_kernel(
    const float* __restrict__ x,
    const float* __restrict__ W1, const float* __restrict__ b1,
    const float* __restrict__ g1, const float* __restrict__ be1,
    const float* __restrict__ W2, const float* __restrict__ b2,
    const float* __restrict__ g2, const float* __restrict__ be2,
    unsigned short* __restrict__ hb, unsigned char* __restrict__ hb8,
    const int* __restrict__ ei, int* __restrict__ cnt, int* __restrict__ bkt,
    int* __restrict__ ovCnt, int2* __restrict__ ov,
    int E, int SB, int TOT)
{
    const int i = blockIdx.x;
    const int before = (int)((long long)i * SB / TOT);
    const int after  = (int)((long long)(i + 1) * SB / TOT);

    if (after > before) {
        scatter_range(ei, cnt, bkt, ovCnt, ov, E, before, 0, HALF);
        return;
    }

    // ---------------- MLP: thread-per-node (all nodes) ----------------
    int gid = (i - before) * 256 + threadIdx.x;
    int node = gid < N_NODES ? gid : N_NODES - 1;

    float xr[D_IN];
    {
        const float4* xp = (const float4*)(x + (long long)node * D_IN);
#pragma unroll
        for (int i2 = 0; i2 < D_IN / 4; ++i2) {
            float4 v = xp[i2];
            xr[4*i2+0] = v.x; xr[4*i2+1] = v.y; xr[4*i2+2] = v.z; xr[4*i2+3] = v.w;
        }
    }

    float h1[H];
#pragma unroll
    for (int jb = 0; jb < H / 4; ++jb) {
        float4 b = *(const float4*)(b1 + jb * 4);
        h1[4*jb+0] = b.x; h1[4*jb+1] = b.y; h1[4*jb+2] = b.z; h1[4*jb+3] = b.w;
    }
#pragma unroll
    for (int k = 0; k < D_IN; ++k) {
        float xk = xr[k];
#pragma unroll
        for (int jb = 0; jb < H / 4; ++jb) {
            float4 w = *(const float4*)(W1 + k * H + jb * 4);
            h1[4*jb+0] += xk * w.x; h1[4*jb+1] += xk * w.y;
            h1[4*jb+2] += xk * w.z; h1[4*jb+3] += xk * w.w;
        }
    }
    {
        float s0=0,s1=0,s2=0,s3=0, q0=0,q1=0,q2=0,q3=0;
#pragma unroll
        for (int j = 0; j < H; j += 4) {
            s0 += h1[j+0]; s1 += h1[j+1]; s2 += h1[j+2]; s3 += h1[j+3];
            q0 += h1[j+0]*h1[j+0]; q1 += h1[j+1]*h1[j+1];
            q2 += h1[j+2]*h1[j+2]; q3 += h1[j+3]*h1[j+3];
        }
        float mu  = (s0+s1+s2+s3) * (1.0f / H);
        float var = (q0+q1+q2+q3) * (1.0f / H) - mu * mu;
        float rs  = rsqrtf(var + EPS);
#pragma unroll
        for (int jb = 0; jb < H / 4; ++jb) {
            float4 g = *(const float4*)(g1 + jb * 4);
            float4 be = *(const float4*)(be1 + jb * 4);
            h1[4*jb+0] = fmaxf((h1[4*jb+0]-mu)*rs*g.x + be.x, 0.0f);
            h1[4*jb+1] = fmaxf((h1[4*jb+1]-mu)*rs*g.y + be.y, 0.0f);
            h1[4*jb+2] = fmaxf((h1[4*jb+2]-mu)*rs*g.z + be.z, 0.0f);
            h1[4*jb+3] = fmaxf((h1[4*jb+3]-mu)*rs*g.w + be.w, 0.0f);
        }
    }

    float h2[H];
#pragma unroll
    for (int jb = 0; jb < H / 4; ++jb) {
        float4 b = *(const float4*)(b2 + jb * 4);
        h2[4*jb+0] = b.x; h2[4*jb+1] = b.y; h2[4*jb+2] = b.z; h2[4*jb+3] = b.w;
    }
#pragma unroll
    for (int k = 0; k < H; ++k) {
        float hk = h1[k];
#pragma unroll
        for (int jb = 0; jb < H / 4; ++jb) {
            float4 w = *(const float4*)(W2 + k * H + jb * 4);
            h2[4*jb+0] += hk * w.x; h2[4*jb+1] += hk * w.y;
            h2[4*jb+2] += hk * w.z; h2[4*jb+3] += hk * w.w;
        }
    }
    {
        float s0=0,s1=0,s2=0,s3=0, q0=0,q1=0,q2=0,q3=0;
#pragma unroll
        for (int j = 0; j < H; j += 4) {
            s0 += h2[j+0]; s1 += h2[j+1]; s2 += h2[j+2]; s3 += h2[j+3];
            q0 += h2[j+0]*h2[j+0]; q1 += h2[j+1]*h2[j+1];
            q2 += h2[j+2]*h2[j+2]; q3 += h2[j+3]*h2[j+3];
        }
        float mu  = (s0+s1+s2+s3) * (1.0f / H);
        float var = (q0+q1+q2+q3) * (1.0f / H) - mu * mu;
        float rs  = rsqrtf(var + EPS);

        unsigned short* hp = hb + (long long)node * H;
        unsigned int w8[H / 4];
#pragma unroll
        for (int jb = 0; jb < H / 4; ++jb) {
            float4 g = *(const float4*)(g2 + jb * 4);
            float4 be = *(const float4*)(be2 + jb * 4);
            float4 v;
            v.x = fmaxf((h2[4*jb+0]-mu)*rs*g.x + be.x, 0.0f);
            v.y = fmaxf((h2[4*jb+1]-mu)*rs*g.y + be.y, 0.0f);
            v.z = fmaxf((h2[4*jb+2]-mu)*rs*g.z + be.z, 0.0f);
            v.w = fmaxf((h2[4*jb+3]-mu)*rs*g.w + be.w, 0.0f);
            ushort4 u;
            u.x = f2bf(v.x); u.y = f2bf(v.y); u.z = f2bf(v.z); u.w = f2bf(v.w);
            *(ushort4*)(hp + 4*jb) = u;
            int lo = __builtin_amdgcn_cvt_pk_fp8_f32(v.x, v.y, 0, false);
            w8[jb] = (unsigned int)__builtin_amdgcn_cvt_pk_fp8_f32(v.z, v.w, lo, true);
        }
        unsigned int* hp8 = (unsigned int*)(hb8 + (long long)node * H);
#pragma unroll
        for (int q = 0; q < H / 16; ++q)
            *(uint4*)(hp8 + q * 4) = make_uint4(w8[4*q+0], w8[4*q+1], w8[4*q+2], w8[4*q+3]);
    }
}

// ================= K2: scatter(dst>=50K) ∥ aggr(dst<50K) =================
__global__ __launch_bounds__(256, 2) void k2_kernel(
    const unsigned short* __restrict__ hb, const unsigned char* __restrict__ hb8,
    const int* __restrict__ ei, int* __restrict__ cnt, int* __restrict__ bkt,
    int* __restrict__ ovCnt, int2* __restrict__ ov,
    float* __restrict__ out,
    int E, int SB, int TOT)
{
    const int i = blockIdx.x;
    const int before = (int)((long long)i * SB / TOT);
    const int after  = (int)((long long)(i + 1) * SB / TOT);

    if (after > before) {
        scatter_range(ei, cnt, bkt, ovCnt, ov, E, before, HALF, N_NODES);
        return;
    }

    const int t    = threadIdx.x & 63;
    const int sub  = t >> 4;
    const int wave = (i - before) * 4 + (threadIdx.x >> 6);
    const int node = wave * 4 + sub;               // [0, 50000): 3125 blocks * 16
    aggr_node(cnt, bkt, hb, hb8, out, ovCnt, ov, node);
}

// ================= K3: aggr(dst>=50K) =================
__global__ __launch_bounds__(256, 2) void k3_kernel(
    const int* __restrict__ cnt, const int* __restrict__ bkt,
    const unsigned short* __restrict__ hb, const unsigned char* __restrict__ hb8,
    float* __restrict__ out,
    const int* __restrict__ ovCnt, const int2* __restrict__ ov)
{
    const int t    = threadIdx.x & 63;
    const int sub  = t >> 4;
    const int wave = blockIdx.x * 4 + (threadIdx.x >> 6);
    const int node = HALF + wave * 4 + sub;        // [50000, 100000)
    aggr_node(cnt, bkt, hb, hb8, out, ovCnt, ov, node);
}

extern "C" void kernel_launch(void* const* d_in, const int* in_sizes, int n_in,
                              void* d_out, int out_size, void* d_ws, size_t ws_size,
                              hipStream_t stream)
{
    const float* x   = (const float*)d_in[0];
    const int*   ei  = (const int*)d_in[1];
    const float* W1  = (const float*)d_in[2];
    const float* b1  = (const float*)d_in[3];
    const float* g1  = (const float*)d_in[4];
    const float* be1 = (const float*)d_in[5];
    const float* W2  = (const float*)d_in[6];
    const float* b2  = (const float*)d_in[7];
    const float* g2  = (const float*)d_in[8];
    const float* be2 = (const float*)d_in[9];

    float* out = (float*)d_out;

    // workspace layout (~32.7 MB)
    char* ws = (char*)d_ws;
    unsigned short* hb    = (unsigned short*)ws;        // 12,800,000 B
    unsigned char*  hb8   = (unsigned char*)(ws + 12800000); // 6,400,000 B
    int*            cnt   = (int*)(ws + 19200000);      //    400,000 B
    int*            ovCnt = (int*)(ws + 19600000);      //         64 B
    int2*           ov    = (int2*)(ws + 19600064);     //    262,144 B
    int*            bkt   = (int*)(ws + 19862208);      // 12,800,000 B (nt-written, never zeroed)

    const int E = in_sizes[1] / 2;

    (void)hipMemsetAsync(cnt, 0, 400064, stream);       // cnt + ovCnt

    const int SB  = ((E + 7) / 8 + 255) / 256;          // 611 scatter chunks
    const int MB  = (N_NODES + 255) / 256;              // 391 mlp blocks
    const int AB  = HALF / 16;                          // 3125 aggr-half blocks

    // K1: scatter half0 ∥ MLP all
    k1_kernel<<<SB + MB, 256, 0, stream>>>(
        x, W1, b1, g1, be1, W2, b2, g2, be2, hb, hb8,
        ei, cnt, bkt, ovCnt, ov, E, SB, SB + MB);

    // K2: scatter half1 ∥ aggr half0  (the overlap experiment)
    k2_kernel<<<SB + AB, 256, 0, stream>>>(
        hb, hb8, ei, cnt, bkt, ovCnt, ov, out, E, SB, SB + AB);

    // K3: aggr half1
    k3_kernel<<<AB, 256, 0, stream>>>(cnt, bkt, hb, hb8, out, ovCnt, ov);
}

// Round 11
// 188.156 us; speedup vs baseline: 1.1826x; 1.1267x over previous
//
#include <hip/hip_runtime.h>

#define N_NODES 100000
#define D_IN 32
#define H 64
#define EPS 1e-5f
#define RSTR 32     // bucket row: 32 entry slots (128B)
#define CAP 32
#define OV_CAP 32768
#define NBINS 196   // bins of 512 dst rows (196*512 = 100352 >= 100000)
#define BINSZ 512
#define BINCAP 7168 // mean 6400, sigma ~80 -> +6 sigma safe; overflow -> ov (exact)

typedef float floatx2 __attribute__((ext_vector_type(2)));

__device__ __forceinline__ unsigned short f2bf(float f) {
    union { float f; unsigned int u; } c; c.f = f;
    unsigned int b = c.u + 0x7FFFu + ((c.u >> 16) & 1u);   // RNE
    return (unsigned short)(b >> 16);
}
__device__ __forceinline__ float bf2f(unsigned short s) {
    union { unsigned int u; float f; } c; c.u = ((unsigned int)s) << 16;
    return c.f;
}

// ================= K_A: LDS radix partition (P1) ∥ MLP =================
// R19: scatter's 2.5M random ops (1.25M cnt atomics + 1.25M bkt stores) are
// the only removable half of the shared random-op wall (R10: read/write walls
// are one resource; gather's 1.25M lines are mandatory). P1 privatizes the
// histogram into LDS: per block one atomic per TOUCHED BIN (~120K total) and
// edge writes clustered into ~196 runs/block (~150K line-touches). No early
// return before __syncthreads (tail threads just carry rows=-1).
__global__ __launch_bounds__(256, 2) void ka_kernel(
    const float* __restrict__ x,
    const float* __restrict__ W1, const float* __restrict__ b1,
    const float* __restrict__ g1, const float* __restrict__ be1,
    const float* __restrict__ W2, const float* __restrict__ b2,
    const float* __restrict__ g2, const float* __restrict__ be2,
    unsigned short* __restrict__ hb, unsigned char* __restrict__ hb8,
    const int* __restrict__ ei, int* __restrict__ part, int* __restrict__ binCur,
    int* __restrict__ ovCnt, int2* __restrict__ ov,
    int E, int SB, int TOT)
{
    const int i = blockIdx.x;
    const int before = (int)((long long)i * SB / TOT);
    const int after  = (int)((long long)(i + 1) * SB / TOT);

    if (after > before) {
        // ---------------- P1: partition 2048 edges into bins ----------------
        __shared__ int hist[NBINS];
        __shared__ int basev[NBINS];

        int t = before * 256 + threadIdx.x;
        int e0 = t * 8;

        int rows[8], cols[8], myofs[8];
        if (e0 + 7 < E) {
            int4 r0 = *(const int4*)(ei + e0);
            int4 r1 = *(const int4*)(ei + e0 + 4);
            int4 c0 = *(const int4*)(ei + E + e0);
            int4 c1 = *(const int4*)(ei + E + e0 + 4);
            rows[0]=r0.x; rows[1]=r0.y; rows[2]=r0.z; rows[3]=r0.w;
            rows[4]=r1.x; rows[5]=r1.y; rows[6]=r1.z; rows[7]=r1.w;
            cols[0]=c0.x; cols[1]=c0.y; cols[2]=c0.z; cols[3]=c0.w;
            cols[4]=c1.x; cols[5]=c1.y; cols[6]=c1.z; cols[7]=c1.w;
        } else {
#pragma unroll
            for (int j = 0; j < 8; ++j) {
                int e = e0 + j;
                if (e < E) { rows[j] = ei[e]; cols[j] = ei[E + e]; }
                else rows[j] = -1;
            }
        }

        if (threadIdx.x < NBINS) hist[threadIdx.x] = 0;
        __syncthreads();

#pragma unroll
        for (int j = 0; j < 8; ++j)
            if (rows[j] >= 0) myofs[j] = atomicAdd(&hist[rows[j] >> 9], 1);
        __syncthreads();

        if (threadIdx.x < NBINS) {
            int h = hist[threadIdx.x];
            if (h > 0) basev[threadIdx.x] = atomicAdd(&binCur[threadIdx.x], h);
        }
        __syncthreads();

#pragma unroll
        for (int j = 0; j < 8; ++j) {
            if (rows[j] < 0) continue;
            int bin  = rows[j] >> 9;
            int slot = basev[bin] + myofs[j];
            if (slot < BINCAP) {
                // pack: r_local (9b) | col (17b); col < 100000 < 2^17
                part[bin * BINCAP + slot] = ((rows[j] & (BINSZ - 1)) << 17) | cols[j];
            } else {
                int s = atomicAdd(ovCnt, 1);
                if (s < OV_CAP) ov[s] = make_int2(rows[j], cols[j]);
            }
        }
        return;
    }

    // ---------------- MLP: thread-per-node (unchanged) ----------------
    int gid = (i - before) * 256 + threadIdx.x;
    int node = gid < N_NODES ? gid : N_NODES - 1;

    float xr[D_IN];
    {
        const float4* xp = (const float4*)(x + (long long)node * D_IN);
#pragma unroll
        for (int i2 = 0; i2 < D_IN / 4; ++i2) {
            float4 v = xp[i2];
            xr[4*i2+0] = v.x; xr[4*i2+1] = v.y; xr[4*i2+2] = v.z; xr[4*i2+3] = v.w;
        }
    }

    float h1[H];
#pragma unroll
    for (int jb = 0; jb < H / 4; ++jb) {
        float4 b = *(const float4*)(b1 + jb * 4);
        h1[4*jb+0] = b.x; h1[4*jb+1] = b.y; h1[4*jb+2] = b.z; h1[4*jb+3] = b.w;
    }
#pragma unroll
    for (int k = 0; k < D_IN; ++k) {
        float xk = xr[k];
#pragma unroll
        for (int jb = 0; jb < H / 4; ++jb) {
            float4 w = *(const float4*)(W1 + k * H + jb * 4);
            h1[4*jb+0] += xk * w.x; h1[4*jb+1] += xk * w.y;
            h1[4*jb+2] += xk * w.z; h1[4*jb+3] += xk * w.w;
        }
    }
    {
        float s0=0,s1=0,s2=0,s3=0, q0=0,q1=0,q2=0,q3=0;
#pragma unroll
        for (int j = 0; j < H; j += 4) {
            s0 += h1[j+0]; s1 += h1[j+1]; s2 += h1[j+2]; s3 += h1[j+3];
            q0 += h1[j+0]*h1[j+0]; q1 += h1[j+1]*h1[j+1];
            q2 += h1[j+2]*h1[j+2]; q3 += h1[j+3]*h1[j+3];
        }
        float mu  = (s0+s1+s2+s3) * (1.0f / H);
        float var = (q0+q1+q2+q3) * (1.0f / H) - mu * mu;
        float rs  = rsqrtf(var + EPS);
#pragma unroll
        for (int jb = 0; jb < H / 4; ++jb) {
            float4 g = *(const float4*)(g1 + jb * 4);
            float4 be = *(const float4*)(be1 + jb * 4);
            h1[4*jb+0] = fmaxf((h1[4*jb+0]-mu)*rs*g.x + be.x, 0.0f);
            h1[4*jb+1] = fmaxf((h1[4*jb+1]-mu)*rs*g.y + be.y, 0.0f);
            h1[4*jb+2] = fmaxf((h1[4*jb+2]-mu)*rs*g.z + be.z, 0.0f);
            h1[4*jb+3] = fmaxf((h1[4*jb+3]-mu)*rs*g.w + be.w, 0.0f);
        }
    }

    float h2[H];
#pragma unroll
    for (int jb = 0; jb < H / 4; ++jb) {
        float4 b = *(const float4*)(b2 + jb * 4);
        h2[4*jb+0] = b.x; h2[4*jb+1] = b.y; h2[4*jb+2] = b.z; h2[4*jb+3] = b.w;
    }
#pragma unroll
    for (int k = 0; k < H; ++k) {
        float hk = h1[k];
#pragma unroll
        for (int jb = 0; jb < H / 4; ++jb) {
            float4 w = *(const float4*)(W2 + k * H + jb * 4);
            h2[4*jb+0] += hk * w.x; h2[4*jb+1] += hk * w.y;
            h2[4*jb+2] += hk * w.z; h2[4*jb+3] += hk * w.w;
        }
    }
    {
        float s0=0,s1=0,s2=0,s3=0, q0=0,q1=0,q2=0,q3=0;
#pragma unroll
        for (int j = 0; j < H; j += 4) {
            s0 += h2[j+0]; s1 += h2[j+1]; s2 += h2[j+2]; s3 += h2[j+3];
            q0 += h2[j+0]*h2[j+0]; q1 += h2[j+1]*h2[j+1];
            q2 += h2[j+2]*h2[j+2]; q3 += h2[j+3]*h2[j+3];
        }
        float mu  = (s0+s1+s2+s3) * (1.0f / H);
        float var = (q0+q1+q2+q3) * (1.0f / H) - mu * mu;
        float rs  = rsqrtf(var + EPS);

        unsigned short* hp = hb + (long long)node * H;
        unsigned int w8[H / 4];
#pragma unroll
        for (int jb = 0; jb < H / 4; ++jb) {
            float4 g = *(const float4*)(g2 + jb * 4);
            float4 be = *(const float4*)(be2 + jb * 4);
            float4 v;
            v.x = fmaxf((h2[4*jb+0]-mu)*rs*g.x + be.x, 0.0f);
            v.y = fmaxf((h2[4*jb+1]-mu)*rs*g.y + be.y, 0.0f);
            v.z = fmaxf((h2[4*jb+2]-mu)*rs*g.z + be.z, 0.0f);
            v.w = fmaxf((h2[4*jb+3]-mu)*rs*g.w + be.w, 0.0f);
            ushort4 u;
            u.x = f2bf(v.x); u.y = f2bf(v.y); u.z = f2bf(v.z); u.w = f2bf(v.w);
            *(ushort4*)(hp + 4*jb) = u;
            int lo = __builtin_amdgcn_cvt_pk_fp8_f32(v.x, v.y, 0, false);
            w8[jb] = (unsigned int)__builtin_amdgcn_cvt_pk_fp8_f32(v.z, v.w, lo, true);
        }
        unsigned int* hp8 = (unsigned int*)(hb8 + (long long)node * H);
#pragma unroll
        for (int q = 0; q < H / 16; ++q)
            *(uint4*)(hp8 + q * 4) = make_uint4(w8[4*q+0], w8[4*q+1], w8[4*q+2], w8[4*q+3]);
    }
}

// ================= K_B: per-bin bucket build in LDS, sequential write-out =================
__global__ __launch_bounds__(256, 2) void kb_kernel(
    const int* __restrict__ part, const int* __restrict__ binCur,
    int* __restrict__ cnt, int* __restrict__ bkt,
    int* __restrict__ ovCnt, int2* __restrict__ ov)
{
    __shared__ int cnt_l[BINSZ];
    __shared__ int bkt_l[BINSZ * CAP];   // 64 KB

    const int bin = blockIdx.x;
    int n = binCur[bin];
    if (n > BINCAP) n = BINCAP;
    const int gbase = bin << 9;

    for (int r = threadIdx.x; r < BINSZ; r += 256) cnt_l[r] = 0;
    __syncthreads();

    const int* p = part + bin * BINCAP;
    for (int idx = threadIdx.x; idx < n; idx += 256) {
        int v = p[idx];
        int r = v >> 17;               // v >= 0 always (26-bit pack)
        int c = v & 0x1FFFF;
        int pos = atomicAdd(&cnt_l[r], 1);
        if (pos < CAP) {
            bkt_l[r * CAP + pos] = c;
        } else {
            int s = atomicAdd(ovCnt, 1);
            if (s < OV_CAP) ov[s] = make_int2(gbase + r, c);
        }
    }
    __syncthreads();

    // sequential copy-out: buckets (8 uint4 per row) then counts
    uint4* gb = (uint4*)bkt;
    const uint4* lb = (const uint4*)bkt_l;
    for (int idx = threadIdx.x; idx < BINSZ * 8; idx += 256) {
        int row = idx >> 3;
        if (gbase + row < N_NODES)
            gb[(long long)(gbase + row) * 8 + (idx & 7)] = lb[idx];
    }
    for (int r = threadIdx.x; r < BINSZ; r += 256)
        if (gbase + r < N_NODES) cnt[gbase + r] = cnt_l[r];
}

// ================= K_C: pull aggregation (R8 dwordx4 form, unchanged) =================
__global__ __launch_bounds__(256, 2) void aggr_kernel(
    const int* __restrict__ cnt, const int* __restrict__ bkt,
    const unsigned short* __restrict__ hb, const unsigned char* __restrict__ hb8,
    float* __restrict__ out,
    const int* __restrict__ ovCnt, const int2* __restrict__ ov)
{
    const int t    = threadIdx.x & 63;
    const int sub  = t >> 4;                       // 4 nodes/wave
    const int l    = t & 15;
    const int q    = l & 3;                        // 16B quad within 64B row
    const int g    = l >> 2;                       // edge-group: 8 contiguous edges
    const int wave = blockIdx.x * 4 + (threadIdx.x >> 6);
    const int node = wave * 4 + sub;               // grid exact: 6250*16 = 100000

    int m = cnt[node];
    if (m > CAP) m = CAP;
    const int base = node * RSTR;

    int4 ea = *(const int4*)(bkt + base + g * 8);
    int4 eb = *(const int4*)(bkt + base + g * 8 + 4);
    int ed[8] = { ea.x, ea.y, ea.z, ea.w, eb.x, eb.y, eb.z, eb.w };
    const int e0 = g * 8;

    const uint4* h84 = (const uint4*)hb8;          // row = 4 uint4 (64B)

    float s[16];
#pragma unroll
    for (int j = 0; j < 16; ++j) s[j] = 0.f;

    uint4 vv[8];
#pragma unroll
    for (int k = 0; k < 8; ++k)
        if (e0 + k < m) vv[k] = h84[(ed[k] << 2) + q];

#pragma unroll
    for (int k = 0; k < 8; ++k) {
        if (e0 + k < m) {
            unsigned int w[4] = { vv[k].x, vv[k].y, vv[k].z, vv[k].w };
#pragma unroll
            for (int u = 0; u < 4; ++u) {
                floatx2 p0 = __builtin_amdgcn_cvt_pk_f32_fp8(w[u], false);
                floatx2 p1 = __builtin_amdgcn_cvt_pk_f32_fp8(w[u], true);
                s[4*u+0] += p0.x; s[4*u+1] += p0.y;
                s[4*u+2] += p1.x; s[4*u+3] += p1.y;
            }
        }
    }

#pragma unroll
    for (int j = 0; j < 16; ++j) {
        s[j] += __shfl_xor(s[j], 4, 64);
        s[j] += __shfl_xor(s[j], 8, 64);
    }

    const int co = q * 16 + g * 4;
    float a0 = s[g*4+0], a1 = s[g*4+1], a2 = s[g*4+2], a3 = s[g*4+3];

    // self term (bf16 precision, sequential access)
    {
        uint2 sv = *(const uint2*)(hb + ((long long)node << 6) + co);
        a0 += bf2f((unsigned short)(sv.x & 0xFFFFu));
        a1 += bf2f((unsigned short)(sv.x >> 16));
        a2 += bf2f((unsigned short)(sv.y & 0xFFFFu));
        a3 += bf2f((unsigned short)(sv.y >> 16));
    }

    // exact overflow drain (normally 0 entries; bin + bucket overflow unified)
    int nov = *ovCnt; if (nov > OV_CAP) nov = OV_CAP;
    for (int i = 0; i < nov; ++i) {
        int2 rc = ov[i];
        if (rc.x == node) {
            uint2 vo = *(const uint2*)(hb + ((long long)rc.y << 6) + co);
            a0 += bf2f((unsigned short)(vo.x & 0xFFFFu));
            a1 += bf2f((unsigned short)(vo.x >> 16));
            a2 += bf2f((unsigned short)(vo.y & 0xFFFFu));
            a3 += bf2f((unsigned short)(vo.y >> 16));
        }
    }

    *(float4*)(out + ((long long)node << 6) + co) = make_float4(a0, a1, a2, a3);
}

extern "C" void kernel_launch(void* const* d_in, const int* in_sizes, int n_in,
                              void* d_out, int out_size, void* d_ws, size_t ws_size,
                              hipStream_t stream)
{
    const float* x   = (const float*)d_in[0];
    const int*   ei  = (const int*)d_in[1];
    const float* W1  = (const float*)d_in[2];
    const float* b1  = (const float*)d_in[3];
    const float* g1  = (const float*)d_in[4];
    const float* be1 = (const float*)d_in[5];
    const float* W2  = (const float*)d_in[6];
    const float* b2  = (const float*)d_in[7];
    const float* g2  = (const float*)d_in[8];
    const float* be2 = (const float*)d_in[9];

    float* out = (float*)d_out;

    // workspace layout (~38.3 MB)
    char* ws = (char*)d_ws;
    unsigned short* hb     = (unsigned short*)ws;             // 12,800,000 B
    unsigned char*  hb8    = (unsigned char*)(ws + 12800000); //  6,400,000 B
    int*            cnt    = (int*)(ws + 19200000);           //    400,000 B (fully written by K_B)
    int*            ovCnt  = (int*)(ws + 19600000);           //         64 B
    int2*           ov     = (int2*)(ws + 19600064);          //    262,144 B
    int*            binCur = (int*)(ws + 19862208);           //        784 B (pad to 832)
    int*            bkt    = (int*)(ws + 19863040);           // 12,800,000 B
    int*            part   = (int*)(ws + 32663040);           //  5,619,712 B (196*7168*4)

    const int E = in_sizes[1] / 2;

    // zero ovCnt + ov-span + binCursor in one memset (19,600,000 .. 19,863,040)
    (void)hipMemsetAsync(ws + 19600000, 0, 263040, stream);

    const int SB = ((E + 7) / 8 + 255) / 256;           // 611 partition chunks
    const int MB = (N_NODES + 255) / 256;               // 391 mlp blocks

    // K_A: radix partition ∥ MLP
    ka_kernel<<<SB + MB, 256, 0, stream>>>(
        x, W1, b1, g1, be1, W2, b2, g2, be2, hb, hb8,
        ei, part, binCur, ovCnt, ov, E, SB, SB + MB);

    // K_B: per-bin LDS bucket build, sequential write-out
    kb_kernel<<<NBINS, 256, 0, stream>>>(part, binCur, cnt, bkt, ovCnt, ov);

    // K_C: pull aggregation (unchanged)
    aggr_kernel<<<N_NODES / 16, 256, 0, stream>>>(cnt, bkt, hb, hb8, out, ovCnt, ov);
}